// Round 18
// baseline (152.229 us; speedup 1.0000x reference)
//
#include <hip/hip_runtime.h>

typedef float  f32x4  __attribute__((ext_vector_type(4)));
typedef float  f32x16 __attribute__((ext_vector_type(16)));
typedef __bf16 bf16x8 __attribute__((ext_vector_type(8)));
typedef __bf16 bf16x4 __attribute__((ext_vector_type(4)));

__device__ __forceinline__ bf16x8 cvt8(float4 a, float4 b) {
    bf16x8 r;
    r[0] = (__bf16)a.x; r[1] = (__bf16)a.y; r[2] = (__bf16)a.z; r[3] = (__bf16)a.w;
    r[4] = (__bf16)b.x; r[5] = (__bf16)b.y; r[6] = (__bf16)b.z; r[7] = (__bf16)b.w;
    return r;
}

// ws layout: [0, 512KB) proj frags (32x32 layout): tile(h,mat,kt16) of 1KB:
//            elem(lane,j): col=h*32+(lane&31), k=kt*16+((lane>>5)<<3)+j
//            [512KB, 640KB) out frags OF[qd*32768 + (ntl*8+kt)*1024 + lane*16] (16x16)
//            [1MB, ...) PV intermediates, A-frag order, 8KB/batch
#define OF_OFF 524288
#define PV_OFF (1u << 20)

// ---- weight prep ----
__global__ void wprep(const float* __restrict__ Wq, const float* __restrict__ Wk,
                      const float* __restrict__ Wv, const float* __restrict__ Woff,
                      const float* __restrict__ Wout, __bf16* __restrict__ ws) {
    int id = blockIdx.x * 256 + threadIdx.x;          // 0..327679
    if (id < 262144) {
        int tile = id >> 9, e = id & 511;
        int lane = e >> 3, j = e & 7;
        int kt = tile & 15, mat = (tile >> 4) & 3, h = tile >> 6;
        int k = kt * 16 + ((lane >> 5) << 3) + j;
        int col = h * 32 + (lane & 31);
        const float* W = (mat == 0) ? Wq : (mat == 1) ? Wk : (mat == 2) ? Wv : Woff;
        ws[id] = (__bf16)W[k * 256 + col];
    } else {
        int i = id - 262144;                          // 0..65535 (16x16 OF frags)
        int tile = i >> 9, e = i & 511;
        int lane = e >> 3, j = e & 7;
        int kt = tile & 7, nt = tile >> 3;
        int k = kt * 32 + (lane >> 4) * 8 + j;
        int col = nt * 16 + (lane & 15);
        ws[262144 + i] = (__bf16)Wout[k * 256 + col];
    }
}

// issue one 32KB stage (h, half): uni layout [mat 4][kt2 8][lane][16B]
__device__ __forceinline__ void stage32(const unsigned char* wsw, int h, int half,
                                        unsigned char* uni, int t) {
    #pragma unroll
    for (int it = 0; it < 4; ++it) {
        int u = t + it * 512;
        int f = u >> 6;                    // mat*8 + kt2
        int kt = half * 8 + (f & 7);
        const void* src = (const void*)(wsw +
            ((((h * 4 + (f >> 3)) * 16) + kt) << 10) + (u & 63) * 16);
        __builtin_amdgcn_global_load_lds(
            (const __attribute__((address_space(1))) unsigned int*)src,
            (__attribute__((address_space(3))) unsigned int*)(uni + u * 16),
            16, 0, 0);
    }
}

// ---- fused kernel: block = 4 batches (2 pairs); GEMM quad-waves 32x32 M=2-batches;
// ---- tail waves = (batch, seq); 2 blocks/CU, grid 512 even ----
__launch_bounds__(512, 3)
__global__ void tsa_one(const float* __restrict__ query, const float* __restrict__ keyh,
                        const float* __restrict__ valh, const float* __restrict__ refpts,
                        unsigned char* __restrict__ wsw,
                        const float* __restrict__ bq, const float* __restrict__ bk,
                        const float* __restrict__ bv, const float* __restrict__ boff,
                        const float* __restrict__ bout, float* __restrict__ out, int b0)
{
    __shared__ __attribute__((aligned(16))) unsigned char uni[32768];     // 32KB B-frag stage
    __shared__ __attribute__((aligned(16))) unsigned char scr_all[24576]; // 4 batches x 6KB
    const int t = threadIdx.x;
    const int lane = t & 63, w = t >> 6, l15 = lane & 15, lhi = lane >> 4;
    const int P = w >> 2, sub = w & 3;     // GEMM quad mapping (pair, role)
    const int pa = w >> 1, role = w & 1;   // tail mapping (batch, seq)
    const long bpair = (long)b0 + (long)blockIdx.x * 4 + P * 2;
    const long bT    = (long)b0 + (long)blockIdx.x * 4 + pa;
    unsigned char* scrT = scr_all + pa * 6144;
    // scr layout per batch: qh[0,1K) kh0[1,2K) kh1[2,3K) vT[3,5K) off[5,6K)
    __bf16* pvg = (__bf16*)(wsw + PV_OFF) + ((long)blockIdx.x * 4 + pa) * 4096;

    // prologue: stage (0, half0)
    stage32(wsw, 0, 0, uni, t);

    // A fragments: 32 rows (2 batches) x 256 k, direct global->reg bf16 (64 VGPR)
    bf16x8 afr[16];
    {
        const float* Asrc = (sub <= 1) ? query : (sub == 2 ? keyh : valh);
        const float* ap = Asrc + bpair * 4096 + (lane & 31) * 256 + ((lane >> 5) << 3);
        #pragma unroll
        for (int kt = 0; kt < 16; ++kt)
            afr[kt] = cvt8(*(const float4*)(ap + kt * 16), *(const float4*)(ap + kt * 16 + 4));
    }
    const f32x4 z = (f32x4){0.f, 0.f, 0.f, 0.f};
    float2 rp = *(const float2*)(refpts + bT * 128 + l15 * 8 + lhi * 2);
    __syncthreads();   // stage (0,0) drained

    for (int h = 0; h < 8; ++h) {
        // per-head bias (col = lane&31)
        const int colv = lane & 31;
        float biasX, biasY = 0.f;
        if (sub == 0)      { biasX = bq[h * 32 + colv]; biasY = boff[h * 32 + colv]; }
        else if (sub == 1) { biasX = bk[h * 32 + colv]; biasY = bv[h * 32 + colv]; }
        else if (sub == 2) { biasX = bk[h * 32 + colv]; }
        else               { biasX = bv[h * 32 + colv]; }

        f32x16 accX = {0,0,0,0,0,0,0,0,0,0,0,0,0,0,0,0};
        f32x16 accY = {0,0,0,0,0,0,0,0,0,0,0,0,0,0,0,0};

        #pragma unroll 2
        for (int half = 0; half < 2; ++half) {
            if (half == 1) {
                __syncthreads();               // uni free
                stage32(wsw, h, 1, uni, t);
                __syncthreads();               // drained (single exposed drain/head)
            }
            #pragma unroll
            for (int kt2 = 0; kt2 < 8; ++kt2) {
                const int kt = half * 8 + kt2;
                const unsigned char* base = uni + kt2 * 1024 + lane * 16;
                if (sub == 0) {
                    bf16x8 bqf = *(const bf16x8*)(base);
                    bf16x8 bof = *(const bf16x8*)(base + 24576);
                    accX = __builtin_amdgcn_mfma_f32_32x32x16_bf16(afr[kt], bqf, accX, 0, 0, 0);
                    accY = __builtin_amdgcn_mfma_f32_32x32x16_bf16(afr[kt], bof, accY, 0, 0, 0);
                } else if (sub == 1) {
                    bf16x8 bkf = *(const bf16x8*)(base + 8192);
                    bf16x8 bvf = *(const bf16x8*)(base + 16384);
                    accX = __builtin_amdgcn_mfma_f32_32x32x16_bf16(afr[kt], bkf, accX, 0, 0, 0);
                    accY = __builtin_amdgcn_mfma_f32_32x32x16_bf16(afr[kt], bvf, accY, 0, 0, 0);
                } else if (sub == 2) {
                    bf16x8 bkf = *(const bf16x8*)(base + 8192);
                    accX = __builtin_amdgcn_mfma_f32_32x32x16_bf16(afr[kt], bkf, accX, 0, 0, 0);
                } else {
                    bf16x8 bvf = *(const bf16x8*)(base + 16384);
                    accX = __builtin_amdgcn_mfma_f32_32x32x16_bf16(afr[kt], bvf, accX, 0, 0, 0);
                }
            }
        }

        // ---- scatter: 32x32 D layout col=lane&31, row=(r&3)+8*(r>>2)+4*(lane>>5) ----
        #pragma unroll
        for (int r = 0; r < 16; ++r) {
            const int row = (r & 3) + ((r >> 2) << 3) + ((lane >> 5) << 2);
            const int q = row & 15;
            unsigned char* sb = scr_all + (P * 2 + (row >> 4)) * 6144;
            if (sub == 0) {
                *(__bf16*)(sb + q * 64 + colv * 2)        = (__bf16)(accX[r] + biasX);
                *(__bf16*)(sb + 5120 + q * 64 + colv * 2) = (__bf16)(accY[r] + biasY);
            } else if (sub == 1) {
                *(__bf16*)(sb + 1024 + q * 64 + colv * 2) = (__bf16)(accX[r] + biasX);
                *(__bf16*)(sb + 3072 + colv * 64 + q * 2) = (__bf16)(accY[r] + biasY);
            } else if (sub == 2) {
                *(__bf16*)(sb + 2048 + q * 64 + colv * 2) = (__bf16)(accX[r] + biasX);
            } else {
                *(__bf16*)(sb + 3072 + colv * 64 + 32 + q * 2) = (__bf16)(accX[r] + biasX);
            }
        }
        __syncthreads();   // B_scr: all projections of head h in scr

        if (h < 7) stage32(wsw, h + 1, 0, uni, t);   // drains at B_wp, hidden under tail

        // ---- S + softmax, own sequence (tail mapping: pa, role) ----
        bf16x8 qf = *(const bf16x8*)(scrT + l15 * 64 + lhi * 16);
        bf16x8 kf = *(const bf16x8*)(scrT + 1024 + role * 1024 + l15 * 64 + lhi * 16);
        f32x4 S = __builtin_amdgcn_mfma_f32_16x16x32_bf16(kf, qf, z, 0, 0, 0);
        float pr4[4];
        {
            float m = fmaxf(fmaxf(S[0], S[1]), fmaxf(S[2], S[3]));
            m = fmaxf(m, __shfl_xor(m, 16)); m = fmaxf(m, __shfl_xor(m, 32));
            float s = 0.f;
            #pragma unroll
            for (int r = 0; r < 4; ++r) { pr4[r] = __expf(S[r] - m); s += pr4[r]; }
            s += __shfl_xor(s, 16); s += __shfl_xor(s, 32);
            float inv = 1.f / s;
            #pragma unroll
            for (int r = 0; r < 4; ++r) pr4[r] *= inv;
        }

        // ---- coords: lane = (q=l15, level=lhi); tent bilinear; own seq weights ----
        {
            bf16x8 off8 = *(const bf16x8*)(scrT + 5120 + l15 * 64 + lhi * 16);
            float w4[4] = {0.f, 0.f, 0.f, 0.f};
            #pragma unroll
            for (int pp = 0; pp < 4; ++pp) {
                float gx = 2.f * rp.x + (float)off8[2 * pp]     - 0.5f;
                float gy = 2.f * rp.y + (float)off8[2 * pp + 1] - 0.5f;
                float tx0 = fmaxf(0.f, 1.f - fabsf(gx));
                float tx1 = fmaxf(0.f, 1.f - fabsf(gx - 1.f));
                float ty0 = fmaxf(0.f, 1.f - fabsf(gy));
                float ty1 = fmaxf(0.f, 1.f - fabsf(gy - 1.f));
                w4[0] += tx0 * ty0 * pr4[pp]; w4[1] += tx1 * ty0 * pr4[pp];
                w4[2] += tx0 * ty1 * pr4[pp]; w4[3] += tx1 * ty1 * pr4[pp];
            }
            *(bf16x4*)(scrT + 1024 + role * 1024 + l15 * 64 + lhi * 8) =
                (bf16x4){(__bf16)w4[0], (__bf16)w4[1], (__bf16)w4[2], (__bf16)w4[3]};
        }
        __syncthreads();   // B_wp: both Wp halves ready; also drains (h+1,0) stage

        // ---- PV: role1 computes both dh halves; wave-local transpose; no B_d ----
        if (role) {
            bf16x8 aW  = *(const bf16x8*)(scrT + 1024 + (lhi >> 1) * 1024 + l15 * 64 + (lhi & 1) * 16);
            bf16x8 vf0 = *(const bf16x8*)(scrT + 3072 + l15 * 64 + lhi * 16);
            bf16x8 vf1 = *(const bf16x8*)(scrT + 3072 + (16 + l15) * 64 + lhi * 16);
            f32x4 c0 = __builtin_amdgcn_mfma_f32_16x16x32_bf16(aW, vf0, z, 0, 0, 0);
            f32x4 c1 = __builtin_amdgcn_mfma_f32_16x16x32_bf16(aW, vf1, z, 0, 0, 0);
            #pragma unroll
            for (int r = 0; r < 4; ++r) {
                int qq = lhi * 4 + r;
                *(__bf16*)(scrT + qq * 64 + l15 * 2)        = (__bf16)(0.5f * c0[r]);
                *(__bf16*)(scrT + qq * 64 + (16 + l15) * 2) = (__bf16)(0.5f * c1[r]);
            }
            bf16x8 pvfrag = *(const bf16x8*)(scrT + l15 * 64 + lhi * 16);
            *(bf16x8*)(pvg + h * 512 + lane * 8) = pvfrag;
        }
    }

    __syncthreads();   // pvg writes visible

    // ---- out-projection: hoisted PV A-frags; B-frags direct from L2; no barriers ----
    {
        bf16x8 pv[8];
        #pragma unroll
        for (int kt = 0; kt < 8; ++kt)
            pv[kt] = *(const bf16x8*)(pvg + kt * 512 + lane * 8);
        for (int qd = 0; qd < 4; ++qd) {
            f32x4 o2[2];
            o2[0] = z; o2[1] = z;
            #pragma unroll
            for (int kt = 0; kt < 8; ++kt) {
                #pragma unroll
                for (int j = 0; j < 2; ++j) {
                    int ntl = role * 2 + j;
                    bf16x8 bfr = *(const bf16x8*)(wsw + OF_OFF + qd * 32768 +
                                                  (ntl * 8 + kt) * 1024 + lane * 16);
                    o2[j] = __builtin_amdgcn_mfma_f32_16x16x32_bf16(pv[kt], bfr, o2[j], 0, 0, 0);
                }
            }
            #pragma unroll
            for (int j = 0; j < 2; ++j) {
                int ntl = role * 2 + j;
                int col = (qd * 4 + ntl) * 16 + l15;
                float bo = bout[col];
                #pragma unroll
                for (int r = 0; r < 4; ++r) {
                    int qq = lhi * 4 + r;
                    long idx = bT * 4096 + qq * 256 + col;
                    out[idx] = o2[j][r] + bo + query[idx];
                }
            }
        }
    }
}

extern "C" void kernel_launch(void* const* d_in, const int* in_sizes, int n_in,
                              void* d_out, int out_size, void* d_ws, size_t ws_size,
                              hipStream_t stream) {
    const float* query      = (const float*)d_in[0];
    const float* key_hist   = (const float*)d_in[1];
    const float* value_hist = (const float*)d_in[2];
    const float* refpts     = (const float*)d_in[3];
    const float* Wq   = (const float*)d_in[5];
    const float* bq   = (const float*)d_in[6];
    const float* Wk   = (const float*)d_in[7];
    const float* bk   = (const float*)d_in[8];
    const float* Wv   = (const float*)d_in[9];
    const float* bv   = (const float*)d_in[10];
    const float* Woff = (const float*)d_in[11];
    const float* boff = (const float*)d_in[12];
    const float* Wout = (const float*)d_in[13];
    const float* bout = (const float*)d_in[14];
    float* outp = (float*)d_out;

    const int bs = in_sizes[0] / 4096;             // 2048
    wprep<<<1280, 256, 0, stream>>>(Wq, Wk, Wv, Woff, Wout, (__bf16*)d_ws);

    long avail = (long)ws_size - (long)PV_OFF;
    int CB = bs;
    if (avail < (long)bs * 8192) {
        CB = (int)(avail / 8192) & ~3;
        if (CB < 4) CB = 4;
    }
    for (int b0 = 0; b0 < bs; b0 += CB) {
        int nb = (bs - b0 < CB ? bs - b0 : CB) / 4;
        tsa_one<<<nb, 512, 0, stream>>>(query, key_hist, value_hist, refpts,
                                        (unsigned char*)d_ws,
                                        bq, bk, bv, boff, bout, outp, b0);
    }
}

// Round 19
// 86.265 us; speedup vs baseline: 1.7647x; 1.7647x over previous
//
#include <hip/hip_runtime.h>

typedef float  f32x4  __attribute__((ext_vector_type(4)));
typedef __bf16 bf16x8 __attribute__((ext_vector_type(8)));
typedef __bf16 bf16x4 __attribute__((ext_vector_type(4)));

__device__ __forceinline__ bf16x8 cvt8(float4 a, float4 b) {
    bf16x8 r;
    r[0] = (__bf16)a.x; r[1] = (__bf16)a.y; r[2] = (__bf16)a.z; r[3] = (__bf16)a.w;
    r[4] = (__bf16)b.x; r[5] = (__bf16)b.y; r[6] = (__bf16)b.z; r[7] = (__bf16)b.w;
    return r;
}

// ws layout: [0, 512KB) proj frags WF[((h*4+mat)*2+nh)*8+kt][lane][8] bf16
//            [512KB, 640KB) out frags OF[qd*32768 + (ntl*8+kt)*1024 + lane*16]
//            [1MB, ...) PV intermediates, A-frag order, 8KB/batch
#define OF_OFF 524288
#define PV_OFF (1u << 20)

// ---- weight prep: fragment-major bf16 ----
__global__ void wprep(const float* __restrict__ Wq, const float* __restrict__ Wk,
                      const float* __restrict__ Wv, const float* __restrict__ Woff,
                      const float* __restrict__ Wout, __bf16* __restrict__ ws) {
    int id = blockIdx.x * 256 + threadIdx.x;          // 0..327679
    if (id < 262144) {
        int tile = id >> 9, e = id & 511;
        int lane = e >> 3, j = e & 7;
        int kt = tile & 7, nh = (tile >> 3) & 1, mat = (tile >> 4) & 3, h = tile >> 6;
        int k = kt * 32 + (lane >> 4) * 8 + j;
        int col = h * 32 + nh * 16 + (lane & 15);
        const float* W = (mat == 0) ? Wq : (mat == 1) ? Wk : (mat == 2) ? Wv : Woff;
        ws[id] = (__bf16)W[k * 256 + col];
    } else {
        int i = id - 262144;                          // 0..65535
        int tile = i >> 9, e = i & 511;
        int lane = e >> 3, j = e & 7;
        int kt = tile & 7, nt = tile >> 3;
        int k = kt * 32 + (lane >> 4) * 8 + j;
        int col = nt * 16 + (lane & 15);
        ws[262144 + i] = (__bf16)Wout[k * 256 + col];
    }
}

// ---- role-split fused kernel: wave-pair = batch, block = 4 batches, 2 blocks/CU ----
__launch_bounds__(512, 4)
__global__ void tsa_one(const float* __restrict__ query, const float* __restrict__ keyh,
                        const float* __restrict__ valh, const float* __restrict__ refpts,
                        unsigned char* __restrict__ wsw,
                        const float* __restrict__ bq, const float* __restrict__ bk,
                        const float* __restrict__ bv, const float* __restrict__ boff,
                        const float* __restrict__ bout, float* __restrict__ out, int b0)
{
    __shared__ __attribute__((aligned(16))) unsigned char uni[16384];     // staged B-frag half
    __shared__ __attribute__((aligned(16))) unsigned char scr_all[24576]; // 4 batches x 6KB
    __shared__ __attribute__((aligned(16))) unsigned char vfr[32768];     // 4 batches x 8KB v A-frags
    const int t = threadIdx.x;
    const int lane = t & 63, w = t >> 6, l15 = lane & 15, lhi = lane >> 4;
    const int p = w >> 1;       // batch within block (0..3)
    const int role = w & 1;     // 0 = Q-wave, 1 = H-wave
    const long b = (long)b0 + (long)blockIdx.x * 4 + p;
    unsigned char* scrp = scr_all + p * 6144;
    // scrp layout: qh[0,1K) kh0[1,2K) kh1[2,3K) vT[3,5K) off[5,6K)
    unsigned char* vfrp = vfr + p * 8192;
    __bf16* pvg = (__bf16*)(wsw + PV_OFF) + ((long)blockIdx.x * 4 + p) * 4096;

    // A fragments: Q-wave = query rows; H-wave = key_hist rows (valh -> LDS frags)
    bf16x8 afr[8];
    {
        const float* s0 = (role ? keyh : query) + b * 4096 + l15 * 256;
        #pragma unroll
        for (int kt = 0; kt < 8; ++kt) {
            int o = kt * 32 + lhi * 8;
            afr[kt] = cvt8(*(const float4*)(s0 + o), *(const float4*)(s0 + o + 4));
        }
        if (role) {
            const float* s1 = valh + b * 4096 + l15 * 256;
            #pragma unroll
            for (int kt = 0; kt < 8; ++kt) {
                int o = kt * 32 + lhi * 8;
                *(bf16x8*)(vfrp + kt * 1024 + lane * 16) =
                    cvt8(*(const float4*)(s1 + o), *(const float4*)(s1 + o + 4));
            }
        }
    }
    const f32x4 z = (f32x4){0.f, 0.f, 0.f, 0.f};
    float2 rp = *(const float2*)(refpts + b * 128 + l15 * 8 + lhi * 2);
    __syncthreads();   // vfr visible

    for (int h = 0; h < 8; ++h) {
        #pragma unroll 2
        for (int nh = 0; nh < 2; ++nh) {
            f32x4 acc[4];
            #pragma unroll
            for (int i = 0; i < 4; ++i) acc[i] = z;
            #pragma unroll 2
            for (int half = 0; half < 2; ++half) {
                __syncthreads();               // uni free
                // DMA 16KB: [mat 4][ktl 4][lane][16B]
                #pragma unroll
                for (int it = 0; it < 2; ++it) {
                    int u = t + it * 512;
                    int f = u >> 6;                    // mat*4 + ktl
                    int kt = (half << 2) + (f & 3);
                    const void* src = (const void*)(wsw +
                        ((((h * 4 + (f >> 2)) * 2 + nh) * 8 + kt) << 10) + (u & 63) * 16);
                    __builtin_amdgcn_global_load_lds(
                        (const __attribute__((address_space(1))) unsigned int*)src,
                        (__attribute__((address_space(3))) unsigned int*)(uni + u * 16),
                        16, 0, 0);
                }
                __syncthreads();               // drained before MFMA
                __builtin_amdgcn_s_setprio(1);
                #pragma unroll
                for (int ktl = 0; ktl < 4; ++ktl) {
                    int kt = (half << 2) + ktl;
                    const unsigned char* bb = uni + ktl * 1024 + lane * 16;
                    bf16x8 b_k = *(const bf16x8*)(bb + 4096);
                    bf16x8 b_v = *(const bf16x8*)(bb + 8192);
                    if (!role) {
                        bf16x8 b_q = *(const bf16x8*)(bb);
                        bf16x8 b_o = *(const bf16x8*)(bb + 12288);
                        acc[0] = __builtin_amdgcn_mfma_f32_16x16x32_bf16(afr[kt], b_q, acc[0], 0, 0, 0);
                        acc[1] = __builtin_amdgcn_mfma_f32_16x16x32_bf16(afr[kt], b_k, acc[1], 0, 0, 0);
                        acc[2] = __builtin_amdgcn_mfma_f32_16x16x32_bf16(afr[kt], b_v, acc[2], 0, 0, 0);
                        acc[3] = __builtin_amdgcn_mfma_f32_16x16x32_bf16(afr[kt], b_o, acc[3], 0, 0, 0);
                    } else {
                        bf16x8 av = *(const bf16x8*)(vfrp + kt * 1024 + lane * 16);
                        acc[0] = __builtin_amdgcn_mfma_f32_16x16x32_bf16(afr[kt], b_k, acc[0], 0, 0, 0);
                        acc[1] = __builtin_amdgcn_mfma_f32_16x16x32_bf16(av,      b_v, acc[1], 0, 0, 0);
                    }
                }
                __builtin_amdgcn_s_setprio(0);
            }
            // per-nh scatter
            {
                int dcol = nh * 16 + l15;
                int gcol = h * 32 + dcol;
                if (!role) {
                    float bqv = bq[gcol], bkv = bk[gcol], bvv = bv[gcol], bov = boff[gcol];
                    #pragma unroll
                    for (int r = 0; r < 4; ++r) {
                        int row = lhi * 4 + r;
                        *(__bf16*)(scrp + row * 64 + dcol * 2)        = (__bf16)(acc[0][r] + bqv);
                        *(__bf16*)(scrp + 1024 + row * 64 + dcol * 2) = (__bf16)(acc[1][r] + bkv);
                        *(__bf16*)(scrp + 3072 + dcol * 64 + row * 2) = (__bf16)(acc[2][r] + bvv);
                        *(__bf16*)(scrp + 5120 + row * 64 + dcol * 2) = (__bf16)(acc[3][r] + bov);
                    }
                } else {
                    float bkv = bk[gcol], bvv = bv[gcol];
                    #pragma unroll
                    for (int r = 0; r < 4; ++r) {
                        int row = lhi * 4 + r;
                        *(__bf16*)(scrp + 2048 + row * 64 + dcol * 2)      = (__bf16)(acc[0][r] + bkv);
                        *(__bf16*)(scrp + 3072 + dcol * 64 + 32 + row * 2) = (__bf16)(acc[1][r] + bvv);
                    }
                }
            }
        }
        __syncthreads();   // B_scr: all projections of head h in scr

        // ---- S + softmax, own sequence (Q: seq0 via kh0, H: seq1 via kh1) ----
        bf16x8 qf = *(const bf16x8*)(scrp + l15 * 64 + lhi * 16);
        bf16x8 kf = *(const bf16x8*)(scrp + 1024 + role * 1024 + l15 * 64 + lhi * 16);
        f32x4 S = __builtin_amdgcn_mfma_f32_16x16x32_bf16(kf, qf, z, 0, 0, 0);
        float pr4[4];
        {
            float m = fmaxf(fmaxf(S[0], S[1]), fmaxf(S[2], S[3]));
            m = fmaxf(m, __shfl_xor(m, 16)); m = fmaxf(m, __shfl_xor(m, 32));
            float s = 0.f;
            #pragma unroll
            for (int r = 0; r < 4; ++r) { pr4[r] = __expf(S[r] - m); s += pr4[r]; }
            s += __shfl_xor(s, 16); s += __shfl_xor(s, 32);
            float inv = 1.f / s;
            #pragma unroll
            for (int r = 0; r < 4; ++r) pr4[r] *= inv;
        }

        // ---- coords: lane = (q=l15, level=lhi); tent bilinear; own seq weights ----
        {
            bf16x8 off8 = *(const bf16x8*)(scrp + 5120 + l15 * 64 + lhi * 16);
            float w4[4] = {0.f, 0.f, 0.f, 0.f};
            #pragma unroll
            for (int pp = 0; pp < 4; ++pp) {
                float gx = 2.f * rp.x + (float)off8[2 * pp]     - 0.5f;
                float gy = 2.f * rp.y + (float)off8[2 * pp + 1] - 0.5f;
                float tx0 = fmaxf(0.f, 1.f - fabsf(gx));
                float tx1 = fmaxf(0.f, 1.f - fabsf(gx - 1.f));
                float ty0 = fmaxf(0.f, 1.f - fabsf(gy));
                float ty1 = fmaxf(0.f, 1.f - fabsf(gy - 1.f));
                w4[0] += tx0 * ty0 * pr4[pp]; w4[1] += tx1 * ty0 * pr4[pp];
                w4[2] += tx0 * ty1 * pr4[pp]; w4[3] += tx1 * ty1 * pr4[pp];
            }
            *(bf16x4*)(scrp + 1024 + role * 1024 + l15 * 64 + lhi * 8) =
                (bf16x4){(__bf16)w4[0], (__bf16)w4[1], (__bf16)w4[2], (__bf16)w4[3]};
        }
        __syncthreads();   // B_wp: both Wp halves ready

        // ---- PV: dh-half = role; K=32 over (2 seqs x 16 positions), 0.5 mean ----
        {
            bf16x8 aW = *(const bf16x8*)(scrp + 1024 + (lhi >> 1) * 1024 + l15 * 64 + (lhi & 1) * 16);
            bf16x8 vf = *(const bf16x8*)(scrp + 3072 + (role * 16 + l15) * 64 + lhi * 16);
            f32x4 c4 = __builtin_amdgcn_mfma_f32_16x16x32_bf16(aW, vf, z, 0, 0, 0);
            #pragma unroll
            for (int r = 0; r < 4; ++r) {
                int qq = lhi * 4 + r;
                *(__bf16*)(scrp + qq * 64 + (role * 16 + l15) * 2) = (__bf16)(0.5f * c4[r]);
            }
        }
        __syncthreads();   // B_d: PV result assembled in qh region
        if (!role) {
            bf16x8 pvfrag = *(const bf16x8*)(scrp + l15 * 64 + lhi * 16);
            *(bf16x8*)(pvg + h * 512 + lane * 8) = pvfrag;
        }
    }

    __syncthreads();   // pvg writes visible to the pair

    // ---- out-projection: hoisted PV A-frags; B-frags direct from L2; no barriers ----
    {
        bf16x8 pv[8];
        #pragma unroll
        for (int kt = 0; kt < 8; ++kt)
            pv[kt] = *(const bf16x8*)(pvg + kt * 512 + lane * 8);
        for (int qd = 0; qd < 4; ++qd) {
            f32x4 o2[2];
            o2[0] = z; o2[1] = z;
            #pragma unroll
            for (int kt = 0; kt < 8; ++kt) {
                #pragma unroll
                for (int j = 0; j < 2; ++j) {
                    int ntl = role * 2 + j;
                    bf16x8 bfr = *(const bf16x8*)(wsw + OF_OFF + qd * 32768 +
                                                  (ntl * 8 + kt) * 1024 + lane * 16);
                    o2[j] = __builtin_amdgcn_mfma_f32_16x16x32_bf16(pv[kt], bfr, o2[j], 0, 0, 0);
                }
            }
            #pragma unroll
            for (int j = 0; j < 2; ++j) {
                int ntl = role * 2 + j;
                int col = (qd * 4 + ntl) * 16 + l15;
                float bo = bout[col];
                #pragma unroll
                for (int r = 0; r < 4; ++r) {
                    int qq = lhi * 4 + r;
                    long idx = b * 4096 + qq * 256 + col;
                    out[idx] = o2[j][r] + bo + query[idx];
                }
            }
        }
    }
}

extern "C" void kernel_launch(void* const* d_in, const int* in_sizes, int n_in,
                              void* d_out, int out_size, void* d_ws, size_t ws_size,
                              hipStream_t stream) {
    const float* query      = (const float*)d_in[0];
    const float* key_hist   = (const float*)d_in[1];
    const float* value_hist = (const float*)d_in[2];
    const float* refpts     = (const float*)d_in[3];
    const float* Wq   = (const float*)d_in[5];
    const float* bq   = (const float*)d_in[6];
    const float* Wk   = (const float*)d_in[7];
    const float* bk   = (const float*)d_in[8];
    const float* Wv   = (const float*)d_in[9];
    const float* bv   = (const float*)d_in[10];
    const float* Woff = (const float*)d_in[11];
    const float* boff = (const float*)d_in[12];
    const float* Wout = (const float*)d_in[13];
    const float* bout = (const float*)d_in[14];
    float* outp = (float*)d_out;

    const int bs = in_sizes[0] / 4096;             // 2048
    wprep<<<1280, 256, 0, stream>>>(Wq, Wk, Wv, Woff, Wout, (__bf16*)d_ws);

    long avail = (long)ws_size - (long)PV_OFF;
    int CB = bs;
    if (avail < (long)bs * 8192) {
        CB = (int)(avail / 8192) & ~3;
        if (CB < 4) CB = 4;
    }
    for (int b0 = 0; b0 < bs; b0 += CB) {
        int nb = (bs - b0 < CB ? bs - b0 : CB) / 4;
        tsa_one<<<nb, 512, 0, stream>>>(query, key_hist, value_hist, refpts,
                                        (unsigned char*)d_ws,
                                        bq, bk, bv, boff, bout, outp, b0);
    }
}

// Round 20
// 84.622 us; speedup vs baseline: 1.7989x; 1.0194x over previous
//
#include <hip/hip_runtime.h>

typedef float  f32x4  __attribute__((ext_vector_type(4)));
typedef __bf16 bf16x8 __attribute__((ext_vector_type(8)));
typedef __bf16 bf16x4 __attribute__((ext_vector_type(4)));

__device__ __forceinline__ bf16x8 cvt8(float4 a, float4 b) {
    bf16x8 r;
    r[0] = (__bf16)a.x; r[1] = (__bf16)a.y; r[2] = (__bf16)a.z; r[3] = (__bf16)a.w;
    r[4] = (__bf16)b.x; r[5] = (__bf16)b.y; r[6] = (__bf16)b.z; r[7] = (__bf16)b.w;
    return r;
}

// ws layout: [0, 512KB) proj frags WF[((h*4+mat)*2+nh)*8+kt][lane][8] bf16
//            [512KB, 640KB) out frags OF[qd*32768 + (ntl*8+kt)*1024 + lane*16]
//            [1MB, ...) PV intermediates, A-frag order, 8KB/batch
#define OF_OFF 524288
#define PV_OFF (1u << 20)

// scr per-batch layout (80B row stride, conflict-free 2-way):
//   qh @0, kh0 @1280, kh1 @2560, vT @3840 (32 rows x 80B), off @6400; total 7680
#define SCRB 7680
#define QH   0
#define KH0  1280
#define KH1  2560
#define VT   3840
#define OFS  6400

// ---- weight prep: fragment-major bf16 ----
__global__ void wprep(const float* __restrict__ Wq, const float* __restrict__ Wk,
                      const float* __restrict__ Wv, const float* __restrict__ Woff,
                      const float* __restrict__ Wout, __bf16* __restrict__ ws) {
    int id = blockIdx.x * 256 + threadIdx.x;          // 0..327679
    if (id < 262144) {
        int tile = id >> 9, e = id & 511;
        int lane = e >> 3, j = e & 7;
        int kt = tile & 7, nh = (tile >> 3) & 1, mat = (tile >> 4) & 3, h = tile >> 6;
        int k = kt * 32 + (lane >> 4) * 8 + j;
        int col = h * 32 + nh * 16 + (lane & 15);
        const float* W = (mat == 0) ? Wq : (mat == 1) ? Wk : (mat == 2) ? Wv : Woff;
        ws[id] = (__bf16)W[k * 256 + col];
    } else {
        int i = id - 262144;                          // 0..65535
        int tile = i >> 9, e = i & 511;
        int lane = e >> 3, j = e & 7;
        int kt = tile & 7, nt = tile >> 3;
        int k = kt * 32 + (lane >> 4) * 8 + j;
        int col = nt * 16 + (lane & 15);
        ws[262144 + i] = (__bf16)Wout[k * 256 + col];
    }
}

// ---- role-split fused kernel: wave-pair = batch, block = 4 batches, 2 blocks/CU ----
__launch_bounds__(512, 4)
__global__ void tsa_one(const float* __restrict__ query, const float* __restrict__ keyh,
                        const float* __restrict__ valh, const float* __restrict__ refpts,
                        unsigned char* __restrict__ wsw,
                        const float* __restrict__ bq, const float* __restrict__ bk,
                        const float* __restrict__ bv, const float* __restrict__ boff,
                        const float* __restrict__ bout, float* __restrict__ out, int b0)
{
    __shared__ __attribute__((aligned(16))) unsigned char uni[16384];       // staged B-frag half
    __shared__ __attribute__((aligned(16))) unsigned char scr_all[4 * SCRB];// 4 batches x 7680
    __shared__ __attribute__((aligned(16))) unsigned char vfr[32768];       // 4 batches x 8KB v A-frags
    const int t = threadIdx.x;
    const int lane = t & 63, w = t >> 6, l15 = lane & 15, lhi = lane >> 4;
    const int p = w >> 1;       // batch within block (0..3)
    const int role = w & 1;     // 0 = Q-wave, 1 = H-wave
    const long b = (long)b0 + (long)blockIdx.x * 4 + p;
    unsigned char* scrp = scr_all + p * SCRB;
    unsigned char* vfrp = vfr + p * 8192;
    __bf16* pvg = (__bf16*)(wsw + PV_OFF) + ((long)blockIdx.x * 4 + p) * 4096;

    // A fragments: Q-wave = query rows; H-wave = key_hist rows (valh -> LDS frags)
    bf16x8 afr[8];
    {
        const float* s0 = (role ? keyh : query) + b * 4096 + l15 * 256;
        #pragma unroll
        for (int kt = 0; kt < 8; ++kt) {
            int o = kt * 32 + lhi * 8;
            afr[kt] = cvt8(*(const float4*)(s0 + o), *(const float4*)(s0 + o + 4));
        }
        if (role) {
            const float* s1 = valh + b * 4096 + l15 * 256;
            #pragma unroll
            for (int kt = 0; kt < 8; ++kt) {
                int o = kt * 32 + lhi * 8;
                *(bf16x8*)(vfrp + kt * 1024 + lane * 16) =
                    cvt8(*(const float4*)(s1 + o), *(const float4*)(s1 + o + 4));
            }
        }
    }
    const f32x4 z = (f32x4){0.f, 0.f, 0.f, 0.f};
    float2 rp = *(const float2*)(refpts + b * 128 + l15 * 8 + lhi * 2);
    __syncthreads();   // vfr visible

    for (int h = 0; h < 8; ++h) {
        #pragma unroll 2
        for (int nh = 0; nh < 2; ++nh) {
            f32x4 acc[4];
            #pragma unroll
            for (int i = 0; i < 4; ++i) acc[i] = z;
            #pragma unroll 2
            for (int half = 0; half < 2; ++half) {
                __syncthreads();               // uni free
                // DMA 16KB: [mat 4][ktl 4][lane][16B]
                #pragma unroll
                for (int it = 0; it < 2; ++it) {
                    int u = t + it * 512;
                    int f = u >> 6;                    // mat*4 + ktl
                    int kt = (half << 2) + (f & 3);
                    const void* src = (const void*)(wsw +
                        ((((h * 4 + (f >> 2)) * 2 + nh) * 8 + kt) << 10) + (u & 63) * 16);
                    __builtin_amdgcn_global_load_lds(
                        (const __attribute__((address_space(1))) unsigned int*)src,
                        (__attribute__((address_space(3))) unsigned int*)(uni + u * 16),
                        16, 0, 0);
                }
                __syncthreads();               // drained before MFMA
                __builtin_amdgcn_s_setprio(1);
                #pragma unroll
                for (int ktl = 0; ktl < 4; ++ktl) {
                    int kt = (half << 2) + ktl;
                    const unsigned char* bb = uni + ktl * 1024 + lane * 16;
                    bf16x8 b_k = *(const bf16x8*)(bb + 4096);
                    bf16x8 b_v = *(const bf16x8*)(bb + 8192);
                    if (!role) {
                        bf16x8 b_q = *(const bf16x8*)(bb);
                        bf16x8 b_o = *(const bf16x8*)(bb + 12288);
                        acc[0] = __builtin_amdgcn_mfma_f32_16x16x32_bf16(afr[kt], b_q, acc[0], 0, 0, 0);
                        acc[1] = __builtin_amdgcn_mfma_f32_16x16x32_bf16(afr[kt], b_k, acc[1], 0, 0, 0);
                        acc[2] = __builtin_amdgcn_mfma_f32_16x16x32_bf16(afr[kt], b_v, acc[2], 0, 0, 0);
                        acc[3] = __builtin_amdgcn_mfma_f32_16x16x32_bf16(afr[kt], b_o, acc[3], 0, 0, 0);
                    } else {
                        bf16x8 av = *(const bf16x8*)(vfrp + kt * 1024 + lane * 16);
                        acc[0] = __builtin_amdgcn_mfma_f32_16x16x32_bf16(afr[kt], b_k, acc[0], 0, 0, 0);
                        acc[1] = __builtin_amdgcn_mfma_f32_16x16x32_bf16(av,      b_v, acc[1], 0, 0, 0);
                    }
                }
                __builtin_amdgcn_s_setprio(0);
            }
            // per-nh scatter (80B row strides)
            {
                int dcol = nh * 16 + l15;
                int gcol = h * 32 + dcol;
                if (!role) {
                    float bqv = bq[gcol], bkv = bk[gcol], bvv = bv[gcol], bov = boff[gcol];
                    #pragma unroll
                    for (int r = 0; r < 4; ++r) {
                        int row = lhi * 4 + r;
                        *(__bf16*)(scrp + QH  + row * 80 + dcol * 2) = (__bf16)(acc[0][r] + bqv);
                        *(__bf16*)(scrp + KH0 + row * 80 + dcol * 2) = (__bf16)(acc[1][r] + bkv);
                        *(__bf16*)(scrp + VT  + dcol * 80 + row * 2) = (__bf16)(acc[2][r] + bvv);
                        *(__bf16*)(scrp + OFS + row * 80 + dcol * 2) = (__bf16)(acc[3][r] + bov);
                    }
                } else {
                    float bkv = bk[gcol], bvv = bv[gcol];
                    #pragma unroll
                    for (int r = 0; r < 4; ++r) {
                        int row = lhi * 4 + r;
                        *(__bf16*)(scrp + KH1 + row * 80 + dcol * 2)      = (__bf16)(acc[0][r] + bkv);
                        *(__bf16*)(scrp + VT  + dcol * 80 + 32 + row * 2) = (__bf16)(acc[1][r] + bvv);
                    }
                }
            }
        }
        __syncthreads();   // B_scr: all projections of head h in scr

        // ---- S + softmax, own sequence (Q: seq0 via kh0, H: seq1 via kh1) ----
        bf16x8 qf = *(const bf16x8*)(scrp + QH + l15 * 80 + lhi * 16);
        bf16x8 kf = *(const bf16x8*)(scrp + KH0 + role * 1280 + l15 * 80 + lhi * 16);
        f32x4 S = __builtin_amdgcn_mfma_f32_16x16x32_bf16(kf, qf, z, 0, 0, 0);
        float pr4[4];
        {
            float m = fmaxf(fmaxf(S[0], S[1]), fmaxf(S[2], S[3]));
            m = fmaxf(m, __shfl_xor(m, 16)); m = fmaxf(m, __shfl_xor(m, 32));
            float s = 0.f;
            #pragma unroll
            for (int r = 0; r < 4; ++r) { pr4[r] = __expf(S[r] - m); s += pr4[r]; }
            s += __shfl_xor(s, 16); s += __shfl_xor(s, 32);
            float inv = 1.f / s;
            #pragma unroll
            for (int r = 0; r < 4; ++r) pr4[r] *= inv;
        }

        // ---- coords: lane = (q=l15, level=lhi); tent bilinear; own seq weights ----
        {
            bf16x8 off8 = *(const bf16x8*)(scrp + OFS + l15 * 80 + lhi * 16);
            float w4[4] = {0.f, 0.f, 0.f, 0.f};
            #pragma unroll
            for (int pp = 0; pp < 4; ++pp) {
                float gx = 2.f * rp.x + (float)off8[2 * pp]     - 0.5f;
                float gy = 2.f * rp.y + (float)off8[2 * pp + 1] - 0.5f;
                float tx0 = fmaxf(0.f, 1.f - fabsf(gx));
                float tx1 = fmaxf(0.f, 1.f - fabsf(gx - 1.f));
                float ty0 = fmaxf(0.f, 1.f - fabsf(gy));
                float ty1 = fmaxf(0.f, 1.f - fabsf(gy - 1.f));
                w4[0] += tx0 * ty0 * pr4[pp]; w4[1] += tx1 * ty0 * pr4[pp];
                w4[2] += tx0 * ty1 * pr4[pp]; w4[3] += tx1 * ty1 * pr4[pp];
            }
            *(bf16x4*)(scrp + KH0 + role * 1280 + l15 * 80 + lhi * 8) =
                (bf16x4){(__bf16)w4[0], (__bf16)w4[1], (__bf16)w4[2], (__bf16)w4[3]};
        }
        __syncthreads();   // B_wp: both Wp halves ready

        // ---- PV: dh-half = role; K=32 over (2 seqs x 16 positions), 0.5 mean ----
        {
            bf16x8 aW = *(const bf16x8*)(scrp + KH0 + (lhi >> 1) * 1280 + l15 * 80 + (lhi & 1) * 16);
            bf16x8 vf = *(const bf16x8*)(scrp + VT + (role * 16 + l15) * 80 + lhi * 16);
            f32x4 c4 = __builtin_amdgcn_mfma_f32_16x16x32_bf16(aW, vf, z, 0, 0, 0);
            #pragma unroll
            for (int r = 0; r < 4; ++r) {
                int qq = lhi * 4 + r;
                *(__bf16*)(scrp + QH + qq * 80 + (role * 16 + l15) * 2) = (__bf16)(0.5f * c4[r]);
            }
        }
        __syncthreads();   // B_d: PV result assembled in qh region
        if (!role) {
            bf16x8 pvfrag = *(const bf16x8*)(scrp + QH + l15 * 80 + lhi * 16);
            *(bf16x8*)(pvg + h * 512 + lane * 8) = pvfrag;
        }
    }

    __syncthreads();   // pvg writes visible to the pair

    // ---- out-projection: hoisted PV A-frags; B-frags direct from L2; no barriers ----
    {
        bf16x8 pv[8];
        #pragma unroll
        for (int kt = 0; kt < 8; ++kt)
            pv[kt] = *(const bf16x8*)(pvg + kt * 512 + lane * 8);
        for (int qd = 0; qd < 4; ++qd) {
            f32x4 o2[2];
            o2[0] = z; o2[1] = z;
            #pragma unroll
            for (int kt = 0; kt < 8; ++kt) {
                #pragma unroll
                for (int j = 0; j < 2; ++j) {
                    int ntl = role * 2 + j;
                    bf16x8 bfr = *(const bf16x8*)(wsw + OF_OFF + qd * 32768 +
                                                  (ntl * 8 + kt) * 1024 + lane * 16);
                    o2[j] = __builtin_amdgcn_mfma_f32_16x16x32_bf16(pv[kt], bfr, o2[j], 0, 0, 0);
                }
            }
            #pragma unroll
            for (int j = 0; j < 2; ++j) {
                int ntl = role * 2 + j;
                int col = (qd * 4 + ntl) * 16 + l15;
                float bo = bout[col];
                #pragma unroll
                for (int r = 0; r < 4; ++r) {
                    int qq = lhi * 4 + r;
                    long idx = b * 4096 + qq * 256 + col;
                    out[idx] = o2[j][r] + bo + query[idx];
                }
            }
        }
    }
}

extern "C" void kernel_launch(void* const* d_in, const int* in_sizes, int n_in,
                              void* d_out, int out_size, void* d_ws, size_t ws_size,
                              hipStream_t stream) {
    const float* query      = (const float*)d_in[0];
    const float* key_hist   = (const float*)d_in[1];
    const float* value_hist = (const float*)d_in[2];
    const float* refpts     = (const float*)d_in[3];
    const float* Wq   = (const float*)d_in[5];
    const float* bq   = (const float*)d_in[6];
    const float* Wk   = (const float*)d_in[7];
    const float* bk   = (const float*)d_in[8];
    const float* Wv   = (const float*)d_in[9];
    const float* bv   = (const float*)d_in[10];
    const float* Woff = (const float*)d_in[11];
    const float* boff = (const float*)d_in[12];
    const float* Wout = (const float*)d_in[13];
    const float* bout = (const float*)d_in[14];
    float* outp = (float*)d_out;

    const int bs = in_sizes[0] / 4096;             // 2048
    wprep<<<1280, 256, 0, stream>>>(Wq, Wk, Wv, Woff, Wout, (__bf16*)d_ws);

    long avail = (long)ws_size - (long)PV_OFF;
    int CB = bs;
    if (avail < (long)bs * 8192) {
        CB = (int)(avail / 8192) & ~3;
        if (CB < 4) CB = 4;
    }
    for (int b0 = 0; b0 < bs; b0 += CB) {
        int nb = (bs - b0 < CB ? bs - b0 : CB) / 4;
        tsa_one<<<nb, 512, 0, stream>>>(query, key_hist, value_hist, refpts,
                                        (unsigned char*)d_ws,
                                        bq, bk, bv, boff, bout, outp, b0);
    }
}

// Round 22
// 79.936 us; speedup vs baseline: 1.9044x; 1.0586x over previous
//
#include <hip/hip_runtime.h>

typedef float  f32x4  __attribute__((ext_vector_type(4)));
typedef __bf16 bf16x8 __attribute__((ext_vector_type(8)));
typedef __bf16 bf16x4 __attribute__((ext_vector_type(4)));

__device__ __forceinline__ bf16x8 cvt8(float4 a, float4 b) {
    bf16x8 r;
    r[0] = (__bf16)a.x; r[1] = (__bf16)a.y; r[2] = (__bf16)a.z; r[3] = (__bf16)a.w;
    r[4] = (__bf16)b.x; r[5] = (__bf16)b.y; r[6] = (__bf16)b.z; r[7] = (__bf16)b.w;
    return r;
}

// ws layout: [0, 512KB) proj frags WF[((h*4+mat)*2+nh)*8+kt][lane][8] bf16
//            [512KB, 640KB) out frags OF[qd*32768 + (ntl*8+kt)*1024 + lane*16]
//            [1MB, ...) PV intermediates, A-frag order, 8KB/batch
#define OF_OFF 524288
#define PV_OFF (1u << 20)

// scr per-batch layout (80B row stride, conflict-free 2-way):
//   qh @0, kh0 @1280, kh1 @2560, vT @3840 (32 rows x 80B), off @6400; total 7680
#define SCRB 7680
#define QH   0
#define KH0  1280
#define KH1  2560
#define VT   3840
#define OFS  6400

// ---- weight prep: fragment-major bf16 ----
__global__ void wprep(const float* __restrict__ Wq, const float* __restrict__ Wk,
                      const float* __restrict__ Wv, const float* __restrict__ Woff,
                      const float* __restrict__ Wout, __bf16* __restrict__ ws) {
    int id = blockIdx.x * 256 + threadIdx.x;          // 0..327679
    if (id < 262144) {
        int tile = id >> 9, e = id & 511;
        int lane = e >> 3, j = e & 7;
        int kt = tile & 7, nh = (tile >> 3) & 1, mat = (tile >> 4) & 3, h = tile >> 6;
        int k = kt * 32 + (lane >> 4) * 8 + j;
        int col = h * 32 + nh * 16 + (lane & 15);
        const float* W = (mat == 0) ? Wq : (mat == 1) ? Wk : (mat == 2) ? Wv : Woff;
        ws[id] = (__bf16)W[k * 256 + col];
    } else {
        int i = id - 262144;                          // 0..65535
        int tile = i >> 9, e = i & 511;
        int lane = e >> 3, j = e & 7;
        int kt = tile & 7, nt = tile >> 3;
        int k = kt * 32 + (lane >> 4) * 8 + j;
        int col = nt * 16 + (lane & 15);
        ws[262144 + i] = (__bf16)Wout[k * 256 + col];
    }
}

// ---- role-split fused kernel: wave-pair = batch, block = 4 batches, 2 blocks/CU ----
__launch_bounds__(512, 4)
__global__ void tsa_one(const float* __restrict__ query, const float* __restrict__ keyh,
                        const float* __restrict__ valh, const float* __restrict__ refpts,
                        unsigned char* __restrict__ wsw,
                        const float* __restrict__ bq, const float* __restrict__ bk,
                        const float* __restrict__ bv, const float* __restrict__ boff,
                        const float* __restrict__ bout, float* __restrict__ out, int b0)
{
    __shared__ __attribute__((aligned(16))) unsigned char uni[16384];       // staged B-frag half
    __shared__ __attribute__((aligned(16))) unsigned char scr_all[4 * SCRB];// 4 batches x 7680
    __shared__ __attribute__((aligned(16))) unsigned char vfr[32768];       // 4 batches x 8KB v A-frags
    const int t = threadIdx.x;
    const int lane = t & 63, w = t >> 6, l15 = lane & 15, lhi = lane >> 4;
    const int p = w >> 1;       // batch within block (0..3)
    const int role = w & 1;     // 0 = Q-wave, 1 = H-wave
    const long b = (long)b0 + (long)blockIdx.x * 4 + p;
    unsigned char* scrp = scr_all + p * SCRB;
    unsigned char* vfrp = vfr + p * 8192;
    __bf16* pvg = (__bf16*)(wsw + PV_OFF) + ((long)blockIdx.x * 4 + p) * 4096;

    // A fragments (declared BEFORE lambdas so they capture correctly)
    bf16x8 afr[8];

    // issue one 16KB stage (h, nh, half): uni layout [mat 4][ktl 4][lane][16B]
    auto stage16 = [&](int h, int nh, int half) {
        #pragma unroll
        for (int it = 0; it < 2; ++it) {
            int u = t + it * 512;
            int f = u >> 6;                    // mat*4 + ktl
            int kt = (half << 2) + (f & 3);
            const void* src = (const void*)(wsw +
                ((((h * 4 + (f >> 2)) * 2 + nh) * 8 + kt) << 10) + (u & 63) * 16);
            __builtin_amdgcn_global_load_lds(
                (const __attribute__((address_space(1))) unsigned int*)src,
                (__attribute__((address_space(3))) unsigned int*)(uni + u * 16),
                16, 0, 0);
        }
    };

    // one 4-kt MFMA burst from uni (half selects afr/vfr k-range)
    auto burst = [&](int half, f32x4* acc) {
        __builtin_amdgcn_s_setprio(1);
        #pragma unroll
        for (int ktl = 0; ktl < 4; ++ktl) {
            int kt = (half << 2) + ktl;
            const unsigned char* bb = uni + ktl * 1024 + lane * 16;
            bf16x8 b_k = *(const bf16x8*)(bb + 4096);
            bf16x8 b_v = *(const bf16x8*)(bb + 8192);
            if (!role) {
                bf16x8 b_q = *(const bf16x8*)(bb);
                bf16x8 b_o = *(const bf16x8*)(bb + 12288);
                acc[0] = __builtin_amdgcn_mfma_f32_16x16x32_bf16(afr[kt], b_q, acc[0], 0, 0, 0);
                acc[1] = __builtin_amdgcn_mfma_f32_16x16x32_bf16(afr[kt], b_k, acc[1], 0, 0, 0);
                acc[2] = __builtin_amdgcn_mfma_f32_16x16x32_bf16(afr[kt], b_v, acc[2], 0, 0, 0);
                acc[3] = __builtin_amdgcn_mfma_f32_16x16x32_bf16(afr[kt], b_o, acc[3], 0, 0, 0);
            } else {
                bf16x8 av = *(const bf16x8*)(vfrp + kt * 1024 + lane * 16);
                acc[0] = __builtin_amdgcn_mfma_f32_16x16x32_bf16(afr[kt], b_k, acc[0], 0, 0, 0);
                acc[1] = __builtin_amdgcn_mfma_f32_16x16x32_bf16(av,      b_v, acc[1], 0, 0, 0);
            }
        }
        __builtin_amdgcn_s_setprio(0);
    };

    auto scatter = [&](int h, int nh, const f32x4* acc) {
        int dcol = nh * 16 + l15;
        int gcol = h * 32 + dcol;
        if (!role) {
            float bqv = bq[gcol], bkv = bk[gcol], bvv = bv[gcol], bov = boff[gcol];
            #pragma unroll
            for (int r = 0; r < 4; ++r) {
                int row = lhi * 4 + r;
                *(__bf16*)(scrp + QH  + row * 80 + dcol * 2) = (__bf16)(acc[0][r] + bqv);
                *(__bf16*)(scrp + KH0 + row * 80 + dcol * 2) = (__bf16)(acc[1][r] + bkv);
                *(__bf16*)(scrp + VT  + dcol * 80 + row * 2) = (__bf16)(acc[2][r] + bvv);
                *(__bf16*)(scrp + OFS + row * 80 + dcol * 2) = (__bf16)(acc[3][r] + bov);
            }
        } else {
            float bkv = bk[gcol], bvv = bv[gcol];
            #pragma unroll
            for (int r = 0; r < 4; ++r) {
                int row = lhi * 4 + r;
                *(__bf16*)(scrp + KH1 + row * 80 + dcol * 2)      = (__bf16)(acc[0][r] + bkv);
                *(__bf16*)(scrp + VT  + dcol * 80 + 32 + row * 2) = (__bf16)(acc[1][r] + bvv);
            }
        }
    };

    // fill A fragments: Q-wave = query rows; H-wave = key_hist rows (valh -> LDS frags)
    {
        const float* s0 = (role ? keyh : query) + b * 4096 + l15 * 256;
        #pragma unroll
        for (int kt = 0; kt < 8; ++kt) {
            int o = kt * 32 + lhi * 8;
            afr[kt] = cvt8(*(const float4*)(s0 + o), *(const float4*)(s0 + o + 4));
        }
        if (role) {
            const float* s1 = valh + b * 4096 + l15 * 256;
            #pragma unroll
            for (int kt = 0; kt < 8; ++kt) {
                int o = kt * 32 + lhi * 8;
                *(bf16x8*)(vfrp + kt * 1024 + lane * 16) =
                    cvt8(*(const float4*)(s1 + o), *(const float4*)(s1 + o + 4));
            }
        }
    }
    const f32x4 z = (f32x4){0.f, 0.f, 0.f, 0.f};
    float2 rp = *(const float2*)(refpts + b * 128 + l15 * 8 + lhi * 2);

    stage16(0, 0, 0);          // prologue stage; drained by the sync below
    __syncthreads();           // vfr visible + stage(0,0,0) drained

    for (int h = 0; h < 8; ++h) {
        f32x4 acc[4];
        // ---- nh = 0 (first stage pre-issued & drained) ----
        #pragma unroll
        for (int i = 0; i < 4; ++i) acc[i] = z;
        burst(0, acc);
        __syncthreads();                 // uni free
        stage16(h, 0, 1);
        __syncthreads();                 // drained
        burst(1, acc);
        __syncthreads();                 // uni free
        stage16(h, 1, 0);
        scatter(h, 0, acc);              // overlaps the DMA latency
        __syncthreads();                 // drained
        // ---- nh = 1 ----
        #pragma unroll
        for (int i = 0; i < 4; ++i) acc[i] = z;
        burst(0, acc);
        __syncthreads();                 // uni free
        stage16(h, 1, 1);
        __syncthreads();                 // drained
        burst(1, acc);
        scatter(h, 1, acc);
        __syncthreads();                 // B_scr (uni free: all waves past burst)
        if (h < 7) stage16(h + 1, 0, 0); // hidden under tail; drained at B_wp

        // ---- S + softmax, own sequence (Q: seq0 via kh0, H: seq1 via kh1) ----
        bf16x8 qf = *(const bf16x8*)(scrp + QH + l15 * 80 + lhi * 16);
        bf16x8 kf = *(const bf16x8*)(scrp + KH0 + role * 1280 + l15 * 80 + lhi * 16);
        f32x4 S = __builtin_amdgcn_mfma_f32_16x16x32_bf16(kf, qf, z, 0, 0, 0);
        float pr4[4];
        {
            float m = fmaxf(fmaxf(S[0], S[1]), fmaxf(S[2], S[3]));
            m = fmaxf(m, __shfl_xor(m, 16)); m = fmaxf(m, __shfl_xor(m, 32));
            float s = 0.f;
            #pragma unroll
            for (int r = 0; r < 4; ++r) { pr4[r] = __expf(S[r] - m); s += pr4[r]; }
            s += __shfl_xor(s, 16); s += __shfl_xor(s, 32);
            float inv = 1.f / s;
            #pragma unroll
            for (int r = 0; r < 4; ++r) pr4[r] *= inv;
        }

        // ---- coords: lane = (q=l15, level=lhi); tent bilinear; own seq weights ----
        {
            bf16x8 off8 = *(const bf16x8*)(scrp + OFS + l15 * 80 + lhi * 16);
            float w4[4] = {0.f, 0.f, 0.f, 0.f};
            #pragma unroll
            for (int pp = 0; pp < 4; ++pp) {
                float gx = 2.f * rp.x + (float)off8[2 * pp]     - 0.5f;
                float gy = 2.f * rp.y + (float)off8[2 * pp + 1] - 0.5f;
                float tx0 = fmaxf(0.f, 1.f - fabsf(gx));
                float tx1 = fmaxf(0.f, 1.f - fabsf(gx - 1.f));
                float ty0 = fmaxf(0.f, 1.f - fabsf(gy));
                float ty1 = fmaxf(0.f, 1.f - fabsf(gy - 1.f));
                w4[0] += tx0 * ty0 * pr4[pp]; w4[1] += tx1 * ty0 * pr4[pp];
                w4[2] += tx0 * ty1 * pr4[pp]; w4[3] += tx1 * ty1 * pr4[pp];
            }
            *(bf16x4*)(scrp + KH0 + role * 1280 + l15 * 80 + lhi * 8) =
                (bf16x4){(__bf16)w4[0], (__bf16)w4[1], (__bf16)w4[2], (__bf16)w4[3]};
        }
        __syncthreads();   // B_wp: both Wp halves ready; drains (h+1,0,0) stage

        // ---- PV: dh-half = role; K=32 over (2 seqs x 16 positions), 0.5 mean ----
        {
            bf16x8 aW = *(const bf16x8*)(scrp + KH0 + (lhi >> 1) * 1280 + l15 * 80 + (lhi & 1) * 16);
            bf16x8 vf = *(const bf16x8*)(scrp + VT + (role * 16 + l15) * 80 + lhi * 16);
            f32x4 c4 = __builtin_amdgcn_mfma_f32_16x16x32_bf16(aW, vf, z, 0, 0, 0);
            #pragma unroll
            for (int r = 0; r < 4; ++r) {
                int qq = lhi * 4 + r;
                *(__bf16*)(scrp + QH + qq * 80 + (role * 16 + l15) * 2) = (__bf16)(0.5f * c4[r]);
            }
        }
        __syncthreads();   // B_d: PV result assembled in qh region
        if (!role) {
            bf16x8 pvfrag = *(const bf16x8*)(scrp + QH + l15 * 80 + lhi * 16);
            *(bf16x8*)(pvg + h * 512 + lane * 8) = pvfrag;
        }
    }

    __syncthreads();   // pvg writes visible to the pair

    // ---- out-projection: hoisted PV A-frags; B-frags direct from L2; no barriers ----
    {
        bf16x8 pv[8];
        #pragma unroll
        for (int kt = 0; kt < 8; ++kt)
            pv[kt] = *(const bf16x8*)(pvg + kt * 512 + lane * 8);
        for (int qd = 0; qd < 4; ++qd) {
            f32x4 o2[2];
            o2[0] = z; o2[1] = z;
            #pragma unroll
            for (int kt = 0; kt < 8; ++kt) {
                #pragma unroll
                for (int j = 0; j < 2; ++j) {
                    int ntl = role * 2 + j;
                    bf16x8 bfr = *(const bf16x8*)(wsw + OF_OFF + qd * 32768 +
                                                  (ntl * 8 + kt) * 1024 + lane * 16);
                    o2[j] = __builtin_amdgcn_mfma_f32_16x16x32_bf16(pv[kt], bfr, o2[j], 0, 0, 0);
                }
            }
            #pragma unroll
            for (int j = 0; j < 2; ++j) {
                int ntl = role * 2 + j;
                int col = (qd * 4 + ntl) * 16 + l15;
                float bo = bout[col];
                #pragma unroll
                for (int r = 0; r < 4; ++r) {
                    int qq = lhi * 4 + r;
                    long idx = b * 4096 + qq * 256 + col;
                    out[idx] = o2[j][r] + bo + query[idx];
                }
            }
        }
    }
}

extern "C" void kernel_launch(void* const* d_in, const int* in_sizes, int n_in,
                              void* d_out, int out_size, void* d_ws, size_t ws_size,
                              hipStream_t stream) {
    const float* query      = (const float*)d_in[0];
    const float* key_hist   = (const float*)d_in[1];
    const float* value_hist = (const float*)d_in[2];
    const float* refpts     = (const float*)d_in[3];
    const float* Wq   = (const float*)d_in[5];
    const float* bq   = (const float*)d_in[6];
    const float* Wk   = (const float*)d_in[7];
    const float* bk   = (const float*)d_in[8];
    const float* Wv   = (const float*)d_in[9];
    const float* bv   = (const float*)d_in[10];
    const float* Woff = (const float*)d_in[11];
    const float* boff = (const float*)d_in[12];
    const float* Wout = (const float*)d_in[13];
    const float* bout = (const float*)d_in[14];
    float* outp = (float*)d_out;

    const int bs = in_sizes[0] / 4096;             // 2048
    wprep<<<1280, 256, 0, stream>>>(Wq, Wk, Wv, Woff, Wout, (__bf16*)d_ws);

    long avail = (long)ws_size - (long)PV_OFF;
    int CB = bs;
    if (avail < (long)bs * 8192) {
        CB = (int)(avail / 8192) & ~3;
        if (CB < 4) CB = 4;
    }
    for (int b0 = 0; b0 < bs; b0 += CB) {
        int nb = (bs - b0 < CB ? bs - b0 : CB) / 4;
        tsa_one<<<nb, 512, 0, stream>>>(query, key_hist, value_hist, refpts,
                                        (unsigned char*)d_ws,
                                        bq, bk, bv, boff, bout, outp, b0);
    }
}